// Round 10
// baseline (101.361 us; speedup 1.0000x reference)
//
#include <hip/hip_runtime.h>
#include <hip/hip_bf16.h>

// Problem constants: B=4, S=512, N=2048, E=1024, QL=32, H=8, D=2, VL=32
// Inputs: 0 embeddings[4,512,1024] 1 keys[4,2048,256] 2 values[4,2048,256]
//         3 ocs[8,1024,2048] 4 Wq[512,1024] 5 bq[512] 6 Wo[1024,512] 7 bo[1024]
//         8 gamma[512] 9 beta[512]       all float32.  Output [4,512,1024] f32.

typedef short  short8 __attribute__((ext_vector_type(8)));
typedef float  f32x4  __attribute__((ext_vector_type(4)));

__device__ __forceinline__ ushort f2bf(float x) {
  union { float f; unsigned int u; } v; v.f = x;
  unsigned int r = v.u + 0x7fffu + ((v.u >> 16) & 1u);
  return (ushort)(r >> 16);
}

// hardware packed f32x2 -> bf16x2 (RNE), 1 instr. Used ONLY where the
// consumer is a DS/shuffle/store op (never directly feeding MFMA).
__device__ __forceinline__ unsigned int cvtpk(float a, float b) {
  unsigned int r;
  asm("v_cvt_pk_bf16_f32 %0, %1, %2" : "=v"(r) : "v"(a), "v"(b));
  return r;
}
__device__ __forceinline__ short8 cvt8(f32x4 a, f32x4 b) {
  union { unsigned int u[4]; short8 s; } r;
  r.u[0] = cvtpk(a[0], a[1]);
  r.u[1] = cvtpk(a[2], a[3]);
  r.u[2] = cvtpk(b[0], b[1]);
  r.u[3] = cvtpk(b[2], b[3]);
  return r.s;
}

#if __has_builtin(__builtin_amdgcn_global_load_lds)
#define OCS_ASYNC 1
__device__ __forceinline__ void gl_lds16(const float* g, float* l) {
  __builtin_amdgcn_global_load_lds(
      (const __attribute__((address_space(1))) unsigned int*)g,
      (__attribute__((address_space(3))) unsigned int*)l, 16, 0, 0);
}
#else
#define OCS_ASYNC 0
#endif

// ---------------------------------------------------------------------------
// prep: keys[b,n,ql*8+h] -> kbf[b,h,n',ql] (bf16) where within each 32-row
// tile, position p = 16s+4gg+r holds source row sigma(p) = 8gg+4s+r. This
// makes the QK^T MFMA output land directly in the K=32 PV B-fragment order
// (lane g holds n = 8g+0..3 from sc0 and 8g+4..7 from sc1) -- no shuffles.
// values[b,n,vl*8+h] -> vbf[b,h,vl,n] (unpermuted).
// ---------------------------------------------------------------------------
__global__ __launch_bounds__(256) void prep_kv(
    const float* __restrict__ keys, const float* __restrict__ values,
    ushort* __restrict__ kbf, ushort* __restrict__ vbf)
{
  __shared__ ushort T[32][264];
  const int bi = blockIdx.x;            // 0..255
  const int b  = bi >> 6;
  const int n0 = (bi & 63) * 32;
  const int t  = threadIdx.x;
  const int nr = t >> 3;                // 0..31
  const int c0 = (t & 7) * 32;          // 0..224

  {
    const float* src = keys + ((size_t)b*2048 + n0 + nr)*256 + c0;
#pragma unroll
    for (int j = 0; j < 32; j += 8) {
      f32x4 x0 = *(const f32x4*)(src + j);
      f32x4 x1 = *(const f32x4*)(src + j + 4);
      *(short8*)&T[nr][c0 + j] = cvt8(x0, x1);
    }
  }
  __syncthreads();
  {
    const int h = t >> 5, nn = t & 31;
    // inverse permutation: source row nn -> tile position pp
    const int pp = 16*((nn >> 2) & 1) + 4*(nn >> 3) + (nn & 3);
    ushort* dst = kbf + (((size_t)(b*8 + h) * 2048) + n0 + pp) * 32;
#pragma unroll
    for (int j = 0; j < 4; j++) {
      short8 w;
#pragma unroll
      for (int i = 0; i < 8; i++) w[i] = (short)T[nn][(j*8 + i)*8 + h];
      *(short8*)(dst + j*8) = w;
    }
  }
  __syncthreads();
  {
    const float* src = values + ((size_t)b*2048 + n0 + nr)*256 + c0;
#pragma unroll
    for (int j = 0; j < 32; j += 8) {
      f32x4 x0 = *(const f32x4*)(src + j);
      f32x4 x1 = *(const f32x4*)(src + j + 4);
      *(short8*)&T[nr][c0 + j] = cvt8(x0, x1);
    }
  }
  __syncthreads();
  {
    const int c = t, h = c & 7, vl = c >> 3;
    ushort* dst = vbf + (((size_t)(b*8 + h) * 32) + vl) * 2048 + n0;
#pragma unroll
    for (int j = 0; j < 4; j++) {
      short8 w;
#pragma unroll
      for (int i = 0; i < 8; i++) w[i] = (short)T[j*8 + i][c];
      *(short8*)(dst + j*8) = w;
    }
  }
}

// ---------------------------------------------------------------------------
// GEMM (NT): out[m,n] = sum_k A[m,k]*B[n,k] + bias[n]. 64x64 tile, 4 waves.
// EPI=0: scatter-store bf16*(1/sqrt(32)) into qbf[b,h,t,ql]; EPI=1: f32 out.
// ---------------------------------------------------------------------------
template<int EPI>
__global__ __launch_bounds__(256) void gemm_nt(
    const float* __restrict__ A, const float* __restrict__ Bm,
    const float* __restrict__ bias, void* __restrict__ outp,
    int M, int N, int K)
{
  __shared__ ushort As[64][32];
  __shared__ ushort Bs[64][32];
  const int tid = threadIdx.x;
  const int m0 = blockIdx.x * 64;
  const int n0 = blockIdx.y * 64;
  const int lane = tid & 63;
  const int wid  = tid >> 6;
  const int wm = wid >> 1, wn = wid & 1;
  const int lt = lane & 15, g = lane >> 4;
  const int lrow = tid >> 2;      // 0..63
  const int lseg = tid & 3;       // 0..3 (8 floats each)
  const int slot_w = lseg ^ ((lrow & 3) ^ ((lrow >> 2) & 3));

  f32x4 acc[2][2] = {};

  for (int k0 = 0; k0 < K; k0 += 32) {
    {
      const float* sa = A + (size_t)(m0 + lrow) * K + k0 + lseg * 8;
      f32x4 a0 = *(const f32x4*)sa;
      f32x4 a1 = *(const f32x4*)(sa + 4);
      *(short8*)&As[lrow][slot_w * 8] = cvt8(a0, a1);
      const float* sb = Bm + (size_t)(n0 + lrow) * K + k0 + lseg * 8;
      f32x4 b0 = *(const f32x4*)sb;
      f32x4 b1 = *(const f32x4*)(sb + 4);
      *(short8*)&Bs[lrow][slot_w * 8] = cvt8(b0, b1);
    }
    __syncthreads();
    short8 af[2], bfr[2];
#pragma unroll
    for (int ss = 0; ss < 2; ss++) {
      const int ra = wm*32 + ss*16 + lt;
      af[ss]  = *(const short8*)&As[ra][(g ^ ((ra & 3) ^ ((ra >> 2) & 3))) * 8];
      const int rb = wn*32 + ss*16 + lt;
      bfr[ss] = *(const short8*)&Bs[rb][(g ^ ((rb & 3) ^ ((rb >> 2) & 3))) * 8];
    }
#pragma unroll
    for (int i = 0; i < 2; i++)
#pragma unroll
      for (int j = 0; j < 2; j++)
        acc[i][j] = __builtin_amdgcn_mfma_f32_16x16x32_bf16(af[i], bfr[j], acc[i][j], 0, 0, 0);
    __syncthreads();
  }

#pragma unroll
  for (int i = 0; i < 2; i++)
#pragma unroll
    for (int j = 0; j < 2; j++) {
      const int n  = n0 + wn*32 + j*16 + lt;
      const float bv = bias[n];
      const int mb = m0 + wm*32 + i*16 + g*4;
#pragma unroll
      for (int r = 0; r < 4; r++) {
        const int mm = mb + r;
        if (EPI == 0) {
          const float val = (acc[i][j][r] + bv) * 0.17677669529663687f;
          const int bb = mm >> 9, s = mm & 511;
          const int d = n >> 8, ql = (n >> 3) & 31, hh = n & 7;
          const int tt = s*2 + d;
          ((ushort*)outp)[((size_t)(bb*8 + hh) * 1024 + tt) * 32 + ql] = f2bf(val);
        } else {
          ((float*)outp)[(size_t)mm * N + n] = acc[i][j][r] + bv;
        }
      }
    }
}

// ---------------------------------------------------------------------------
// Attention (split-n). R8/R9 math, deeper pipeline: 8-buffer LDS ocs ring
// (DMA distance 4 steps), K/V prefetch distance 2 steps into alternating
// named register sets, 2 steps (one pair) computed per barrier with their
// exp/pack chains interleaved. VMEM issue order per pair = [8 K/V, 2 DMA]:
// the compiler's K/V wait (vmcnt(2)) leaves DMAs in flight; the pair-end
// vmcnt(10) retires only the pair-old DMAs. Barrier count halves.
// ---------------------------------------------------------------------------
__global__ __launch_bounds__(256) void attn_kernel(
    const ushort* __restrict__ qbf, const ushort* __restrict__ kbf,
    const ushort* __restrict__ vbf, const float* __restrict__ ocs,
    float* __restrict__ pacc, float* __restrict__ pl, int nsteps)
{
#if OCS_ASYNC
  __shared__ float obuf[8][1024];   // ring: 8 x [32 rows][8 slots][4 f32]
#endif
  const int tid  = threadIdx.x;
  const int lane = tid & 63;
  const int c  = blockIdx.x >> 8;
  const int bi = blockIdx.x & 255;
  const int wid = bi * 4 + (tid >> 6);
  const int b  = wid & 3;
  const int tt = (wid >> 2) & 31;
  const int h  = wid >> 7;
  const int t0 = tt * 32;
  const int lt = lane & 15, g = lane >> 4;
  const int n_start = c * nsteps * 32;

  const ushort* qp = qbf + (size_t)(b*8 + h) * (1024*32);
  const ushort* kp = kbf + (size_t)(b*8 + h) * (2048*32);
  const ushort* vp = vbf + (size_t)(b*8 + h) * (32*2048);
  const float*  op = ocs + (size_t)h * (1024*2048);

#define NSX(I) (((I) < nsteps) ? (n_start + (I)*32) : n_start)

  // ocs staging: thread -> row (tid>>3), slot (tid&7); source col is
  // inverse-swizzled so LDS slot s holds global cols 4*(s^(row&7))..+3.
  const int srow = tid >> 3;
  const int scol = 4 * ((tid & 7) ^ (srow & 7));
  const float* sb = op + (size_t)(t0 + srow) * 2048 + scol;
#if OCS_ASYNC
  const int ldsw = (tid & 192) * 16;   // per-wave LDS byte base (lane*16 added by HW)
#define SL_ISSUE(STEP) gl_lds16(sb + NSX(STEP), \
    (float*)((char*)obuf + (((STEP) & 7) << 12) + ldsw))
  // swizzled read offsets: sc0 cols 8g..8g+3 (slot 2g), sc1 cols 8g+4..8g+7
  // (slot 2g+1); row ts*16+lt.
  const int ro0 = lt * 128;            // ts=0 row byte offset
  const int ro1 = (16 + lt) * 128;     // ts=1
  const int c0x = ((2*g)     ^ (lt & 7)) * 16;   // sc0 slot bytes
  const int c1x = ((2*g + 1) ^ (lt & 7)) * 16;   // sc1 slot bytes
#define CO_READ(DST, STEP) do {                                               \
    const char* bb_ = (const char*)obuf + (((STEP) & 7) << 12);               \
    DST[0][0] = *(const f32x4*)(bb_ + ro0 + c0x);                             \
    DST[1][0] = *(const f32x4*)(bb_ + ro0 + c1x);                             \
    DST[0][1] = *(const f32x4*)(bb_ + ro1 + c0x);                             \
    DST[1][1] = *(const f32x4*)(bb_ + ro1 + c1x);                             \
  } while (0)
#define PAIR_SYNC() do {                                                      \
    __builtin_amdgcn_sched_barrier(0);                                        \
    asm volatile("s_waitcnt vmcnt(10)" ::: "memory");                         \
    __builtin_amdgcn_sched_barrier(0);                                        \
    __builtin_amdgcn_s_barrier();                                             \
  } while (0)
#else
  const float* opr0 = op + (size_t)(t0 + lt) * 2048;
  const float* opr1 = op + (size_t)(t0 + 16 + lt) * 2048;
#define SL_ISSUE(STEP)
#define CO_READ(DST, STEP) do {                                               \
    const int nn_ = NSX(STEP);                                                \
    DST[0][0] = *(const f32x4*)(opr0 + nn_ + 8*g);                            \
    DST[1][0] = *(const f32x4*)(opr0 + nn_ + 8*g + 4);                        \
    DST[0][1] = *(const f32x4*)(opr1 + nn_ + 8*g);                            \
    DST[1][1] = *(const f32x4*)(opr1 + nn_ + 8*g + 4);                        \
  } while (0)
#define PAIR_SYNC()
#endif

#define LD_KV(KD, VD, NN) do {                                                \
    KD[0] = *(const short8*)(kp + (size_t)((NN) + lt) * 32 + g*8);            \
    KD[1] = *(const short8*)(kp + (size_t)((NN) + 16 + lt) * 32 + g*8);       \
    VD[0] = *(const short8*)(vp + (size_t)lt * 2048 + (NN) + g*8);            \
    VD[1] = *(const short8*)(vp + (size_t)(16 + lt) * 2048 + (NN) + g*8);     \
  } while (0)

  short8 qf[2];
#pragma unroll
  for (int ts = 0; ts < 2; ts++)
    qf[ts] = *(const short8*)(qp + (t0 + ts*16 + lt)*32 + g*8);

  f32x4 acc[2][2] = {};
  float lsum[2] = {0.f, 0.f};
  const f32x4 fzero = {0.f, 0.f, 0.f, 0.f};

  // ts-block: exp + f2bf pack (P already in B-frag order via permuted K) + PV
#define TSB(SC0, SC1, CO0, CO1, VLO, VHI, LS, ACCA, ACCB) do {                \
    float p0 = __expf(SC0[0] - CO0[0]);                                       \
    float p1 = __expf(SC0[1] - CO0[1]);                                       \
    float p2 = __expf(SC0[2] - CO0[2]);                                       \
    float p3 = __expf(SC0[3] - CO0[3]);                                       \
    float p4 = __expf(SC1[0] - CO1[0]);                                       \
    float p5 = __expf(SC1[1] - CO1[1]);                                       \
    float p6 = __expf(SC1[2] - CO1[2]);                                       \
    float p7 = __expf(SC1[3] - CO1[3]);                                       \
    LS += ((p0+p1)+(p2+p3)) + ((p4+p5)+(p6+p7));                              \
    union { unsigned int u[4]; short8 s; } pf;                                \
    pf.u[0] = (unsigned int)f2bf(p0) | ((unsigned int)f2bf(p1) << 16);        \
    pf.u[1] = (unsigned int)f2bf(p2) | ((unsigned int)f2bf(p3) << 16);        \
    pf.u[2] = (unsigned int)f2bf(p4) | ((unsigned int)f2bf(p5) << 16);        \
    pf.u[3] = (unsigned int)f2bf(p6) | ((unsigned int)f2bf(p7) << 16);        \
    ACCA = __builtin_amdgcn_mfma_f32_16x16x32_bf16(VLO, pf.s, ACCA, 0, 0, 0); \
    ACCB = __builtin_amdgcn_mfma_f32_16x16x32_bf16(VHI, pf.s, ACCB, 0, 0, 0); \
  } while (0)

  // One pair = steps SA_, SA_+1. Consumes KV set (KC,VC); loads (KN,VN) for
  // steps SA_+2,SA_+3; stages ocs DMA for steps SA_+4,SA_+5.
#define PAIR(SA_, KC, VC, KN, VN) do {                                        \
    const int sA_ = (SA_);                                                    \
    LD_KV(KN[0], VN[0], NSX(sA_ + 2));                                        \
    LD_KV(KN[1], VN[1], NSX(sA_ + 3));                                        \
    SL_ISSUE(sA_ + 4);                                                        \
    SL_ISSUE(sA_ + 5);                                                        \
    __builtin_amdgcn_sched_barrier(0);                                        \
    f32x4 coA[2][2], coB[2][2];                                               \
    CO_READ(coA, sA_);                                                        \
    CO_READ(coB, sA_ + 1);                                                    \
    f32x4 scA0[2], scA1[2], scB0[2], scB1[2];                                 \
    _Pragma("unroll")                                                         \
    for (int ts = 0; ts < 2; ts++) {                                          \
      scA0[ts] = __builtin_amdgcn_mfma_f32_16x16x32_bf16(KC[0][0], qf[ts], fzero, 0, 0, 0); \
      scA1[ts] = __builtin_amdgcn_mfma_f32_16x16x32_bf16(KC[0][1], qf[ts], fzero, 0, 0, 0); \
      scB0[ts] = __builtin_amdgcn_mfma_f32_16x16x32_bf16(KC[1][0], qf[ts], fzero, 0, 0, 0); \
      scB1[ts] = __builtin_amdgcn_mfma_f32_16x16x32_bf16(KC[1][1], qf[ts], fzero, 0, 0, 0); \
    }                                                                         \
    TSB(scA0[0], scA1[0], coA[0][0], coA[1][0], VC[0][0], VC[0][1], lsum[0], acc[0][0], acc[0][1]); \
    TSB(scB0[0], scB1[0], coB[0][0], coB[1][0], VC[1][0], VC[1][1], lsum[0], acc[0][0], acc[0][1]); \
    TSB(scA0[1], scA1[1], coA[0][1], coA[1][1], VC[0][0], VC[0][1], lsum[1], acc[1][0], acc[1][1]); \
    TSB(scB0[1], scB1[1], coB[0][1], coB[1][1], VC[1][0], VC[1][1], lsum[1], acc[1][0], acc[1][1]); \
    PAIR_SYNC();                                                              \
  } while (0)

  // named K/V register sets: K*[pair-step][half], V*[pair-step][half]
  short8 KA[2][2], VA[2][2], KB[2][2], VB[2][2];

  // prologue: KV for steps 0,1 into set A; DMA steps 0..3 into ring 0..3.
  LD_KV(KA[0], VA[0], NSX(0));
  LD_KV(KA[1], VA[1], NSX(1));
#if OCS_ASYNC
  SL_ISSUE(0); SL_ISSUE(1); SL_ISSUE(2); SL_ISSUE(3);
  __builtin_amdgcn_sched_barrier(0);
  asm volatile("s_waitcnt vmcnt(2)" ::: "memory");   // bufs 0,1 ready; D2,D3 in flight
  __builtin_amdgcn_s_barrier();
#endif

  for (int s = 0; s < nsteps; s += 4) {
    PAIR(s,     KA, VA, KB, VB);   // steps s,s+1; load B for s+2,s+3
    PAIR(s + 2, KB, VB, KA, VA);   // steps s+2,s+3; load A for s+4,s+5
  }
#undef PAIR
#undef TSB
#undef LD_KV
#undef CO_READ
#undef SL_ISSUE
#undef PAIR_SYNC
#undef NSX

  // write partials: acc rows [((c*1024+wid)*4 + q)*256 + lane*4], q = ts*2+vs
  {
    float* pb = pacc + ((size_t)(c*1024 + wid) * 4) * 256 + lane * 4;
#pragma unroll
    for (int ts = 0; ts < 2; ts++)
#pragma unroll
      for (int vs = 0; vs < 2; vs++)
        *(f32x4*)(pb + (ts*2 + vs) * 256) = acc[ts][vs];
  }
  // reduce lsum over the 4 g-groups (columns are per-lt), store 32 per wid
#pragma unroll
  for (int ts = 0; ts < 2; ts++) {
    float L = lsum[ts];
    L += __shfl_xor(L, 16);
    L += __shfl_xor(L, 32);
    if (g == 0) pl[((size_t)(c*1024 + wid)) * 32 + ts*16 + lt] = L;
  }
}

// ---------------------------------------------------------------------------
// Combine partials across NS chunks, normalize, write vo[b*512+s][h*64+d*32+..]
// ---------------------------------------------------------------------------
__global__ __launch_bounds__(256) void combine_kernel(
    const float* __restrict__ pacc, const float* __restrict__ pl,
    float* __restrict__ vo, int NS)
{
  const int lane = threadIdx.x & 63;
  const int wid = blockIdx.x * 4 + (threadIdx.x >> 6);
  const int b  = wid & 3;
  const int tt = (wid >> 2) & 31;
  const int h  = wid >> 7;
  const int t0 = tt * 32;
  const int lt = lane & 15, g = lane >> 4;

  f32x4 acc[4] = {};
  float L[2] = {0.f, 0.f};
  for (int cc = 0; cc < NS; ++cc) {
    const float* pb = pacc + ((size_t)(cc*1024 + wid) * 4) * 256 + lane * 4;
#pragma unroll
    for (int q = 0; q < 4; q++) {
      f32x4 v = *(const f32x4*)(pb + q * 256);
#pragma unroll
      for (int r = 0; r < 4; r++) acc[q][r] += v[r];
    }
    L[0] += pl[((size_t)(cc*1024 + wid)) * 32 + lt];
    L[1] += pl[((size_t)(cc*1024 + wid)) * 32 + 16 + lt];
  }
#pragma unroll
  for (int ts = 0; ts < 2; ts++) {
    const float inv = 1.0f / L[ts];
    const int t = t0 + ts*16 + lt;
    const int s = t >> 1, d = t & 1;
    float* dst = vo + ((size_t)(b*512 + s) * 512) + h*64 + d*32;
#pragma unroll
    for (int vs = 0; vs < 2; vs++) {
      f32x4 o;
#pragma unroll
      for (int r = 0; r < 4; r++) o[r] = acc[ts*2 + vs][r] * inv;
      *(f32x4*)(dst + vs*16 + g*4) = o;
    }
  }
}

// ---------------------------------------------------------------------------
// LayerNorm over 512, one wave per row.
// ---------------------------------------------------------------------------
__global__ __launch_bounds__(256) void ln_kernel(
    const float* __restrict__ x_in, const float* __restrict__ gamma,
    const float* __restrict__ beta, float* __restrict__ x_out)
{
  const int row  = blockIdx.x * 4 + (threadIdx.x >> 6);
  const int lane = threadIdx.x & 63;
  const float* x = x_in + (size_t)row * 512 + lane * 8;
  f32x4 v0 = *(const f32x4*)x;
  f32x4 v1 = *(const f32x4*)(x + 4);
  float s = (v0[0]+v0[1]+v0[2]+v0[3]) + (v1[0]+v1[1]+v1[2]+v1[3]);
#pragma unroll
  for (int off = 1; off < 64; off <<= 1) s += __shfl_xor(s, off);
  const float mean = s * (1.0f/512.0f);
  float var = 0.f;
#pragma unroll
  for (int i = 0; i < 4; i++) {
    float d0 = v0[i]-mean, d1 = v1[i]-mean;
    var += d0*d0 + d1*d1;
  }
#pragma unroll
  for (int off = 1; off < 64; off <<= 1) var += __shfl_xor(var, off);
  const float rstd = rsqrtf(var * (1.0f/512.0f) + 1e-5f);
  const float* gp = gamma + lane*8;
  const float* bp = beta  + lane*8;
  f32x4 g0 = *(const f32x4*)gp, g1 = *(const f32x4*)(gp+4);
  f32x4 b0 = *(const f32x4*)bp, b1 = *(const f32x4*)(bp+4);
  f32x4 o0, o1;
#pragma unroll
  for (int i = 0; i < 4; i++) {
    o0[i] = (v0[i]-mean)*rstd*g0[i] + b0[i];
    o1[i] = (v1[i]-mean)*rstd*g1[i] + b1[i];
  }
  float* o = x_out + (size_t)row * 512 + lane * 8;
  *(f32x4*)o = o0;
  *(f32x4*)(o + 4) = o1;
}

// ---------------------------------------------------------------------------
extern "C" void kernel_launch(void* const* d_in, const int* in_sizes, int n_in,
                              void* d_out, int out_size, void* d_ws, size_t ws_size,
                              hipStream_t stream)
{
  const float* emb    = (const float*)d_in[0];
  const float* keys   = (const float*)d_in[1];
  const float* values = (const float*)d_in[2];
  const float* ocs    = (const float*)d_in[3];
  const float* Wq     = (const float*)d_in[4];
  const float* bq     = (const float*)d_in[5];
  const float* Wo     = (const float*)d_in[6];
  const float* bo     = (const float*)d_in[7];
  const float* gamma  = (const float*)d_in[8];
  const float* beta   = (const float*)d_in[9];

  char* ws = (char*)d_ws;
  ushort* qbf = (ushort*)(ws);                    // 2 MB  [b,h,t,ql] bf16
  ushort* kbf = (ushort*)(ws + (2u << 20));       // 4 MB  [b,h,n',ql] bf16 (permuted tiles)
  ushort* vbf = (ushort*)(ws + (6u << 20));       // 4 MB  [b,h,vl,n] bf16
  float*  vo  = (float*) (ws + (10u << 20));      // 4 MB  [m,512] f32
  const size_t pbase = (size_t)14u << 20;

  int NS;
  if      (ws_size >= ((size_t)31u << 20)) NS = 4;   // pacc 16MB + pl 0.5MB
  else if (ws_size >= ((size_t)23u << 20)) NS = 2;
  else                                     NS = 1;
  float* pacc = (float*)(ws + pbase);                            // NS*4MB
  float* pl   = (float*)(ws + pbase + (size_t)NS * (4u << 20));  // NS*128KB
  const int nsteps = 2048 / (NS * 32);

  prep_kv<<<dim3(256), dim3(256), 0, stream>>>(keys, values, kbf, vbf);
  gemm_nt<0><<<dim3(32, 8), dim3(256), 0, stream>>>(emb, Wq, bq, (void*)qbf, 2048, 512, 1024);
  attn_kernel<<<dim3(256 * NS), dim3(256), 0, stream>>>(qbf, kbf, vbf, ocs, pacc, pl, nsteps);
  combine_kernel<<<dim3(256), dim3(256), 0, stream>>>(pacc, pl, vo, NS);
  ln_kernel<<<dim3(512), dim3(256), 0, stream>>>(vo, gamma, beta, vo);
  gemm_nt<1><<<dim3(32, 16), dim3(256), 0, stream>>>(vo, Wo, bo, d_out, 2048, 1024, 512);
}